// Round 1
// baseline (1041.472 us; speedup 1.0000x reference)
//
#include <hip/hip_runtime.h>
#include <hip/hip_bf16.h>
#include <cstdint>

#define D_MODEL 768
#define D_COND  128
#define D_STATE 64
#define D_CONVW 4
#define D_INNER 1536
#define DT_RANK 48
#define NBATCH  4
#define SEQ     2048
#define NROWS   (NBATCH*SEQ)          // 8192
#define DBC_W   (DT_RANK + 2*D_STATE) // 176

typedef __bf16 bf16x8 __attribute__((ext_vector_type(8)));
typedef float  f32x4  __attribute__((ext_vector_type(4)));

__device__ __forceinline__ unsigned short f2bf(float f) {
    unsigned int u = __float_as_uint(f);
    u = (u + 0x7FFFu + ((u >> 16) & 1u)) >> 16;
    return (unsigned short)u;
}
__device__ __forceinline__ float bf2f(unsigned short h) {
    return __uint_as_float(((unsigned int)h) << 16);
}

template<int CTRL>
__device__ __forceinline__ float dpp_add(float x) {
    int yi = __builtin_amdgcn_update_dpp(0, __float_as_int(x), CTRL, 0xF, 0xF, true);
    return x + __int_as_float(yi);
}

// ---------------- prep: f32 -> bf16 (4 elems/thread) ----------------
__global__ void k_cvt(const float* __restrict__ in, unsigned short* __restrict__ out, int n4) {
    int i = blockIdx.x * blockDim.x + threadIdx.x;
    if (i >= n4) return;
    float4 v = ((const float4*)in)[i];
    ushort4 o;
    o.x = f2bf(v.x); o.y = f2bf(v.y); o.z = f2bf(v.z); o.w = f2bf(v.w);
    ((ushort4*)out)[i] = o;
}

// dt_proj_w (1536 x 48) -> transposed f32 (48 x 1536)
__global__ void k_dtw_t(const float* __restrict__ w, float* __restrict__ wt) {
    int id = blockIdx.x * 256 + threadIdx.x;
    if (id >= DT_RANK * D_INNER) return;
    int r = id / D_INNER, d = id % D_INNER;
    wt[id] = w[d * DT_RANK + r];
}

// ---------------- MFMA bf16 GEMM: C[M,N] = A[M,K] * B[N,K]^T (+bias) ----------------
// tile 128x128, 256 threads (4 waves, 2x2), K-step 32, padded LDS (40 ushorts/row)
__global__ __launch_bounds__(256) void k_gemm(
    const unsigned short* __restrict__ A,
    const unsigned short* __restrict__ B,
    const float* __restrict__ bias,
    float* __restrict__ Cf, unsigned short* __restrict__ Cb,
    int M, int N, int K)
{
    __shared__ uint4 sA[128 * 5];
    __shared__ uint4 sB[128 * 5];
    const int tid  = threadIdx.x;
    const int lane = tid & 63;
    const int wid  = tid >> 6;
    const int wr   = wid >> 1, wc = wid & 1;
    const int bm   = blockIdx.y, bn = blockIdx.x;

    f32x4 acc[4][4];
#pragma unroll
    for (int m = 0; m < 4; ++m)
#pragma unroll
        for (int n = 0; n < 4; ++n) { f32x4 z = {0.f,0.f,0.f,0.f}; acc[m][n] = z; }

    const int r = tid >> 1, h = tid & 1;
    const size_t arow = (size_t)(bm * 128 + r);
    const int    brow = bn * 128 + r;
    const bool   bvalid = brow < N;
    const uint4* gA = (const uint4*)(A + arow * (size_t)K);
    const uint4* gB = (const uint4*)(B + (size_t)(bvalid ? brow : 0) * (size_t)K);

    const bf16x8* pA = (const bf16x8*)sA;
    const bf16x8* pB = (const bf16x8*)sB;
    const int kq = lane >> 4;
    const int rr = lane & 15;

    for (int k0 = 0; k0 < K; k0 += 32) {
        int e = (k0 + h * 16) >> 3;                 // uint4 index into row
        uint4 va0 = gA[e], va1 = gA[e + 1];
        uint4 vb0 = make_uint4(0,0,0,0), vb1 = make_uint4(0,0,0,0);
        if (bvalid) { vb0 = gB[e]; vb1 = gB[e + 1]; }
        __syncthreads();
        sA[r * 5 + h * 2]     = va0;
        sA[r * 5 + h * 2 + 1] = va1;
        sB[r * 5 + h * 2]     = vb0;
        sB[r * 5 + h * 2 + 1] = vb1;
        __syncthreads();

        bf16x8 af[4], bg[4];
#pragma unroll
        for (int m = 0; m < 4; ++m) af[m] = pA[(wr * 64 + m * 16 + rr) * 5 + kq];
#pragma unroll
        for (int n = 0; n < 4; ++n) bg[n] = pB[(wc * 64 + n * 16 + rr) * 5 + kq];
#pragma unroll
        for (int m = 0; m < 4; ++m)
#pragma unroll
            for (int n = 0; n < 4; ++n)
                acc[m][n] = __builtin_amdgcn_mfma_f32_16x16x32_bf16(af[m], bg[n], acc[m][n], 0, 0, 0);
    }

    const int rq = lane >> 4;
#pragma unroll
    for (int m = 0; m < 4; ++m) {
#pragma unroll
        for (int n = 0; n < 4; ++n) {
#pragma unroll
            for (int j = 0; j < 4; ++j) {
                int row  = wr * 64 + m * 16 + rq * 4 + j;
                int col  = wc * 64 + n * 16 + rr;
                int gcol = bn * 128 + col;
                if (gcol < N) {
                    size_t grow = (size_t)(bm * 128 + row);
                    float v = acc[m][n][j];
                    if (bias) v += bias[gcol];
                    if (Cf) Cf[grow * (size_t)N + gcol] = v;
                    else    Cb[grow * (size_t)N + gcol] = f2bf(v);
                }
            }
        }
    }
}

// ---------------- causal depthwise conv (w=4) + bias + SiLU -> bf16 ----------------
__global__ void k_conv(const unsigned short* __restrict__ xz, const float* __restrict__ cw,
                       const float* __restrict__ cb, unsigned short* __restrict__ xc)
{
    int idx = blockIdx.x * 256 + threadIdx.x;     // NROWS * 384
    if (idx >= NROWS * (D_INNER / 4)) return;
    int d4 = idx % (D_INNER / 4);
    int m  = idx / (D_INNER / 4);
    int l  = m & (SEQ - 1);
    int d0 = d4 * 4;

    float a0 = cb[d0], a1 = cb[d0 + 1], a2 = cb[d0 + 2], a3 = cb[d0 + 3];
    const float* w0 = cw + (size_t)d0 * 4;
#pragma unroll
    for (int j = 0; j < 4; ++j) {
        int ls = l - 3 + j;
        if (ls < 0) continue;
        const unsigned short* p = xz + (size_t)(m - 3 + j) * (2 * D_INNER) + d0;
        ushort4 v = *(const ushort4*)p;
        a0 += bf2f(v.x) * w0[j];
        a1 += bf2f(v.y) * w0[4 + j];
        a2 += bf2f(v.z) * w0[8 + j];
        a3 += bf2f(v.w) * w0[12 + j];
    }
    ushort4 o;
    o.x = f2bf(a0 / (1.f + __expf(-a0)));
    o.y = f2bf(a1 / (1.f + __expf(-a1)));
    o.z = f2bf(a2 / (1.f + __expf(-a2)));
    o.w = f2bf(a3 / (1.f + __expf(-a3)));
    ((ushort4*)xc)[idx] = o;
}

// ---------------- dt = softplus(dbc[:, :48] @ dtwT + dtb) ----------------
__global__ __launch_bounds__(256) void k_dt(const float* __restrict__ dbc, const float* __restrict__ dtwT,
                                            const float* __restrict__ dtb, float* __restrict__ dt)
{
    __shared__ float s[DT_RANK];
    int m = blockIdx.x;
    int t = threadIdx.x;
    if (t < DT_RANK) s[t] = dbc[(size_t)m * DBC_W + t];
    __syncthreads();
    float a[6] = {0.f, 0.f, 0.f, 0.f, 0.f, 0.f};
    for (int r = 0; r < DT_RANK; ++r) {
        float sv = s[r];
        const float* wr_ = dtwT + (size_t)r * D_INNER;
#pragma unroll
        for (int i = 0; i < 6; ++i) a[i] += sv * wr_[t + i * 256];
    }
#pragma unroll
    for (int i = 0; i < 6; ++i) {
        int d = t + i * 256;
        float x = a[i] + dtb[d];
        float sp = (x > 15.f) ? x : __logf(1.f + __expf(x));
        dt[(size_t)m * D_INNER + d] = sp;
    }
}

// ---------------- selective scan: 1 wave = 4 channels, 16 lanes/chan, 4 states/lane ----------------
__global__ __launch_bounds__(64) void k_scan(
    const float* __restrict__ dbc, const float* __restrict__ dtv_,
    const unsigned short* __restrict__ xcb, const unsigned short* __restrict__ xzb,
    const float* __restrict__ A_log, const float* __restrict__ Dskip,
    unsigned short* __restrict__ yg, float* __restrict__ st_out)
{
    const int lane = threadIdx.x;
    const int g = lane >> 4, s = lane & 15;
    const int bid = blockIdx.x;                    // 0..1535
    const int b = bid / (D_INNER / 4);
    const int d = (bid % (D_INNER / 4)) * 4 + g;
    const int n0 = 4 * s;

    float A2[4];
#pragma unroll
    for (int j = 0; j < 4; ++j)
        A2[j] = -__expf(A_log[(size_t)d * D_STATE + n0 + j]) * 1.4426950408889634f;
    const float Dsk = Dskip[d];
    const size_t mrow = (size_t)b * SEQ;

    const float* Bp = dbc + mrow * DBC_W + DT_RANK + n0;
    const float* Cp = Bp + D_STATE;
    const float* dtp = dtv_ + mrow * D_INNER + d;
    const unsigned short* xcp = xcb + mrow * D_INNER + d;
    const unsigned short* zp  = xzb + mrow * (2 * D_INNER) + D_INNER + d;
    unsigned short* ygp = yg + mrow * D_INNER + d;

    float h0 = 0.f, h1 = 0.f, h2 = 0.f, h3 = 0.f;
    float4 Bv = *(const float4*)Bp;
    float4 Cv = *(const float4*)Cp;
    float dtc = *dtp;
    float xcc = bf2f(*xcp);
    float zc  = bf2f(*zp);

#pragma unroll 4
    for (int l = 0; l < SEQ; ++l) {
        const int ln = (l + 1 < SEQ) ? (l + 1) : l;
        float4 Bn = *(const float4*)(Bp + (size_t)ln * DBC_W);
        float4 Cn = *(const float4*)(Cp + (size_t)ln * DBC_W);
        float dtn = dtp[(size_t)ln * D_INNER];
        float xcn = bf2f(xcp[(size_t)ln * D_INNER]);
        float zn  = bf2f(zp[(size_t)ln * (2 * D_INNER)]);

        float dxc = dtc * xcc;
        h0 = exp2f(dtc * A2[0]) * h0 + dxc * Bv.x;
        h1 = exp2f(dtc * A2[1]) * h1 + dxc * Bv.y;
        h2 = exp2f(dtc * A2[2]) * h2 + dxc * Bv.z;
        h3 = exp2f(dtc * A2[3]) * h3 + dxc * Bv.w;
        float p = h0 * Cv.x + h1 * Cv.y + h2 * Cv.z + h3 * Cv.w;
        p = dpp_add<0xB1>(p);    // xor 1 (quad_perm [1,0,3,2])
        p = dpp_add<0x4E>(p);    // xor 2 (quad_perm [2,3,0,1])
        p = dpp_add<0x124>(p);   // row_ror:4
        p = dpp_add<0x128>(p);   // row_ror:8  -> all 16 lanes hold group sum
        float y = p + Dsk * xcc;
        float gate = __fdividef(zc, 1.f + __expf(-zc));
        if (s == 0) ygp[(size_t)l * D_INNER] = f2bf(y * gate);
        Bv = Bn; Cv = Cn; dtc = dtn; xcc = xcn; zc = zn;
    }
    float4 hf; hf.x = h0; hf.y = h1; hf.z = h2; hf.w = h3;
    *(float4*)(st_out + ((size_t)b * D_INNER + d) * D_STATE + n0) = hf;
}

// ---------------- ada: ss = cond @ ada_w^T + ada_b ----------------
__global__ void k_ada(const float* __restrict__ cond, const float* __restrict__ aw,
                      const float* __restrict__ ab, float* __restrict__ ss)
{
    __shared__ float c[D_COND];
    int bid = blockIdx.x;            // 24 = 4 batches * 6 segments
    int b = bid / 6, seg = bid % 6;
    int t = threadIdx.x;
    if (t < D_COND) c[t] = cond[b * D_COND + t];
    __syncthreads();
    int o = seg * 256 + t;
    float a = 0.f;
    const float* w = aw + (size_t)o * D_COND;
    for (int k = 0; k < D_COND; ++k) a += c[k] * w[k];
    ss[b * 2 * D_MODEL + o] = a + ab[o];
}

// ---------------- residual + LN(w,b) + LN(none)*(1+scale)+shift ----------------
__global__ __launch_bounds__(256) void k_lnmod(
    const float* __restrict__ x, const float* __restrict__ mam,
    const float* __restrict__ lnw, const float* __restrict__ lnb,
    const float* __restrict__ ss, float* __restrict__ out)
{
    int lane = threadIdx.x & 63;
    int w = threadIdx.x >> 6;
    size_t row = (size_t)blockIdx.x * 4 + w;
    int b = (int)(row >> 11);
    const float* xp = x + row * D_MODEL;
    const float* mp = mam + row * D_MODEL;
    float t[12];
    float s1 = 0.f, s2 = 0.f;
#pragma unroll
    for (int i = 0; i < 12; ++i) {
        int c = lane + i * 64;
        t[i] = xp[c] + mp[c];
        s1 += t[i]; s2 += t[i] * t[i];
    }
#pragma unroll
    for (int off = 1; off < 64; off <<= 1) { s1 += __shfl_xor(s1, off); s2 += __shfl_xor(s2, off); }
    float mean = s1 * (1.f / 768.f);
    float var  = s2 * (1.f / 768.f) - mean * mean;
    float rs = rsqrtf(var + 1e-5f);
    float u1 = 0.f, u2 = 0.f;
#pragma unroll
    for (int i = 0; i < 12; ++i) {
        int c = lane + i * 64;
        t[i] = (t[i] - mean) * rs * lnw[c] + lnb[c];
        u1 += t[i]; u2 += t[i] * t[i];
    }
#pragma unroll
    for (int off = 1; off < 64; off <<= 1) { u1 += __shfl_xor(u1, off); u2 += __shfl_xor(u2, off); }
    float m2 = u1 * (1.f / 768.f);
    float v2 = u2 * (1.f / 768.f) - m2 * m2;
    float rs2 = rsqrtf(v2 + 1e-5f);
    const float* sc = ss + (size_t)b * 2 * D_MODEL;
    const float* sh = sc + D_MODEL;
#pragma unroll
    for (int i = 0; i < 12; ++i) {
        int c = lane + i * 64;
        out[row * D_MODEL + c] = (t[i] - m2) * rs2 * (1.f + sc[c]) + sh[c];
    }
}

extern "C" void kernel_launch(void* const* d_in, const int* in_sizes, int n_in,
                              void* d_out, int out_size, void* d_ws, size_t ws_size,
                              hipStream_t stream)
{
    (void)in_sizes; (void)n_in; (void)out_size; (void)ws_size;
    const float* x    = (const float*)d_in[0];
    const float* cond = (const float*)d_in[1];
    const float* w1   = (const float*)d_in[2];
    const float* b1   = (const float*)d_in[3];
    const float* cw   = (const float*)d_in[4];
    const float* cb   = (const float*)d_in[5];
    const float* xpw  = (const float*)d_in[6];
    const float* dtw  = (const float*)d_in[7];
    const float* dtb  = (const float*)d_in[8];
    const float* Alog = (const float*)d_in[9];
    const float* Dsk  = (const float*)d_in[10];
    const float* ow   = (const float*)d_in[11];
    const float* ob   = (const float*)d_in[12];
    const float* lnw  = (const float*)d_in[13];
    const float* lnb  = (const float*)d_in[14];
    const float* aw   = (const float*)d_in[15];
    const float* ab   = (const float*)d_in[16];
    float* out = (float*)d_out;

    char* ws = (char*)d_ws;
    size_t off = 0;
    auto alloc = [&](size_t bytes) -> char* {
        off = (off + 255) & ~(size_t)255;
        char* p = ws + off;
        off += bytes;
        return p;
    };
    unsigned short* xb   = (unsigned short*)alloc((size_t)NROWS * D_MODEL * 2);
    unsigned short* w1b  = (unsigned short*)alloc((size_t)2 * D_INNER * D_MODEL * 2);
    unsigned short* xpwb = (unsigned short*)alloc((size_t)DBC_W * D_INNER * 2);
    unsigned short* owb  = (unsigned short*)alloc((size_t)D_MODEL * D_INNER * 2);
    float*          dtwT = (float*)alloc((size_t)DT_RANK * D_INNER * 4);
    unsigned short* xzb  = (unsigned short*)alloc((size_t)NROWS * 2 * D_INNER * 2);
    unsigned short* xcb  = (unsigned short*)alloc((size_t)NROWS * D_INNER * 2);
    float*          dbc  = (float*)alloc((size_t)NROWS * DBC_W * 4);
    float*          dtb_ = (float*)alloc((size_t)NROWS * D_INNER * 4);
    unsigned short* ygb  = (unsigned short*)alloc((size_t)NROWS * D_INNER * 2);
    float*          mam  = (float*)alloc((size_t)NROWS * D_MODEL * 4);
    float*          ssb  = (float*)alloc((size_t)NBATCH * 2 * D_MODEL * 4);
    // total ~203 MB

    // prep conversions
    {
        int n4 = NROWS * D_MODEL / 4;
        k_cvt<<<(n4 + 255) / 256, 256, 0, stream>>>(x, xb, n4);
        n4 = 2 * D_INNER * D_MODEL / 4;
        k_cvt<<<(n4 + 255) / 256, 256, 0, stream>>>(w1, w1b, n4);
        n4 = DBC_W * D_INNER / 4;
        k_cvt<<<(n4 + 255) / 256, 256, 0, stream>>>(xpw, xpwb, n4);
        n4 = D_MODEL * D_INNER / 4;
        k_cvt<<<(n4 + 255) / 256, 256, 0, stream>>>(ow, owb, n4);
        k_dtw_t<<<(DT_RANK * D_INNER + 255) / 256, 256, 0, stream>>>(dtw, dtwT);
    }
    // in_proj: (8192 x 3072, K=768) -> xzb (bf16, +bias)
    k_gemm<<<dim3(2 * D_INNER / 128, NROWS / 128), 256, 0, stream>>>(
        xb, w1b, b1, nullptr, xzb, NROWS, 2 * D_INNER, D_MODEL);
    // conv + silu -> xcb
    k_conv<<<(NROWS * (D_INNER / 4) + 255) / 256, 256, 0, stream>>>(xzb, cw, cb, xcb);
    // x_proj: (8192 x 176, K=1536) -> dbc (f32)
    k_gemm<<<dim3((DBC_W + 127) / 128, NROWS / 128), 256, 0, stream>>>(
        xcb, xpwb, nullptr, dbc, nullptr, NROWS, DBC_W, D_INNER);
    // dt
    k_dt<<<NROWS, 256, 0, stream>>>(dbc, dtwT, dtb, dtb_);
    // scan (also writes final state to out2)
    k_scan<<<NBATCH * (D_INNER / 4), 64, 0, stream>>>(
        dbc, dtb_, xcb, xzb, Alog, Dsk, ygb, out + (size_t)NROWS * D_MODEL);
    // out_proj: (8192 x 768, K=1536) -> mam (f32, +bias)
    k_gemm<<<dim3(D_MODEL / 128, NROWS / 128), 256, 0, stream>>>(
        ygb, owb, ob, mam, nullptr, NROWS, D_MODEL, D_INNER);
    // ada
    k_ada<<<NBATCH * 6, 256, 0, stream>>>(cond, aw, ab, ssb);
    // residual + double LN + modulation
    k_lnmod<<<NROWS / 4, 256, 0, stream>>>(x, mam, lnw, lnb, ssb, out);
}

// Round 2
// 998.299 us; speedup vs baseline: 1.0432x; 1.0432x over previous
//
#include <hip/hip_runtime.h>
#include <hip/hip_bf16.h>
#include <cstdint>

#define D_MODEL 768
#define D_COND  128
#define D_STATE 64
#define D_CONVW 4
#define D_INNER 1536
#define DT_RANK 48
#define NBATCH  4
#define SEQ     2048
#define NROWS   (NBATCH*SEQ)          // 8192
#define DBC_W   (DT_RANK + 2*D_STATE) // 176
#define NCHUNK  8
#define CLEN    (SEQ/NCHUNK)          // 256

typedef __bf16 bf16x8 __attribute__((ext_vector_type(8)));
typedef float  f32x4  __attribute__((ext_vector_type(4)));

__device__ __forceinline__ unsigned short f2bf(float f) {
    unsigned int u = __float_as_uint(f);
    u = (u + 0x7FFFu + ((u >> 16) & 1u)) >> 16;
    return (unsigned short)u;
}
__device__ __forceinline__ float bf2f(unsigned short h) {
    return __uint_as_float(((unsigned int)h) << 16);
}

template<int CTRL>
__device__ __forceinline__ float dpp_add(float x) {
    int yi = __builtin_amdgcn_update_dpp(0, __float_as_int(x), CTRL, 0xF, 0xF, true);
    return x + __int_as_float(yi);
}

// ---------------- prep: f32 -> bf16 (4 elems/thread) ----------------
__global__ void k_cvt(const float* __restrict__ in, unsigned short* __restrict__ out, int n4) {
    int i = blockIdx.x * blockDim.x + threadIdx.x;
    if (i >= n4) return;
    float4 v = ((const float4*)in)[i];
    ushort4 o;
    o.x = f2bf(v.x); o.y = f2bf(v.y); o.z = f2bf(v.z); o.w = f2bf(v.w);
    ((ushort4*)out)[i] = o;
}

// dt_proj_w (1536 x 48) -> transposed f32 (48 x 1536)
__global__ void k_dtw_t(const float* __restrict__ w, float* __restrict__ wt) {
    int id = blockIdx.x * 256 + threadIdx.x;
    if (id >= DT_RANK * D_INNER) return;
    int r = id / D_INNER, d = id % D_INNER;
    wt[id] = w[d * DT_RANK + r];
}

// ---------------- MFMA bf16 GEMM: C[M,N] = A[M,K] * B[N,K]^T (+bias) ----------------
__global__ __launch_bounds__(256) void k_gemm(
    const unsigned short* __restrict__ A,
    const unsigned short* __restrict__ B,
    const float* __restrict__ bias,
    float* __restrict__ Cf, unsigned short* __restrict__ Cb,
    int M, int N, int K)
{
    __shared__ uint4 sA[128 * 5];
    __shared__ uint4 sB[128 * 5];
    const int tid  = threadIdx.x;
    const int lane = tid & 63;
    const int wid  = tid >> 6;
    const int wr   = wid >> 1, wc = wid & 1;
    const int bm   = blockIdx.y, bn = blockIdx.x;

    f32x4 acc[4][4];
#pragma unroll
    for (int m = 0; m < 4; ++m)
#pragma unroll
        for (int n = 0; n < 4; ++n) { f32x4 z = {0.f,0.f,0.f,0.f}; acc[m][n] = z; }

    const int r = tid >> 1, h = tid & 1;
    const size_t arow = (size_t)(bm * 128 + r);
    const int    brow = bn * 128 + r;
    const bool   bvalid = brow < N;
    const uint4* gA = (const uint4*)(A + arow * (size_t)K);
    const uint4* gB = (const uint4*)(B + (size_t)(bvalid ? brow : 0) * (size_t)K);

    const bf16x8* pA = (const bf16x8*)sA;
    const bf16x8* pB = (const bf16x8*)sB;
    const int kq = lane >> 4;
    const int rr = lane & 15;

    for (int k0 = 0; k0 < K; k0 += 32) {
        int e = (k0 + h * 16) >> 3;                 // uint4 index into row
        uint4 va0 = gA[e], va1 = gA[e + 1];
        uint4 vb0 = make_uint4(0,0,0,0), vb1 = make_uint4(0,0,0,0);
        if (bvalid) { vb0 = gB[e]; vb1 = gB[e + 1]; }
        __syncthreads();
        sA[r * 5 + h * 2]     = va0;
        sA[r * 5 + h * 2 + 1] = va1;
        sB[r * 5 + h * 2]     = vb0;
        sB[r * 5 + h * 2 + 1] = vb1;
        __syncthreads();

        bf16x8 af[4], bg[4];
#pragma unroll
        for (int m = 0; m < 4; ++m) af[m] = pA[(wr * 64 + m * 16 + rr) * 5 + kq];
#pragma unroll
        for (int n = 0; n < 4; ++n) bg[n] = pB[(wc * 64 + n * 16 + rr) * 5 + kq];
#pragma unroll
        for (int m = 0; m < 4; ++m)
#pragma unroll
            for (int n = 0; n < 4; ++n)
                acc[m][n] = __builtin_amdgcn_mfma_f32_16x16x32_bf16(af[m], bg[n], acc[m][n], 0, 0, 0);
    }

    const int rq = lane >> 4;
#pragma unroll
    for (int m = 0; m < 4; ++m) {
#pragma unroll
        for (int n = 0; n < 4; ++n) {
#pragma unroll
            for (int j = 0; j < 4; ++j) {
                int row  = wr * 64 + m * 16 + rq * 4 + j;
                int col  = wc * 64 + n * 16 + rr;
                int gcol = bn * 128 + col;
                if (gcol < N) {
                    size_t grow = (size_t)(bm * 128 + row);
                    float v = acc[m][n][j];
                    if (bias) v += bias[gcol];
                    if (Cf) Cf[grow * (size_t)N + gcol] = v;
                    else    Cb[grow * (size_t)N + gcol] = f2bf(v);
                }
            }
        }
    }
}

// ---------------- causal depthwise conv (w=4) + bias + SiLU -> bf16 ----------------
__global__ void k_conv(const unsigned short* __restrict__ xz, const float* __restrict__ cw,
                       const float* __restrict__ cb, unsigned short* __restrict__ xc)
{
    int idx = blockIdx.x * 256 + threadIdx.x;     // NROWS * 384
    if (idx >= NROWS * (D_INNER / 4)) return;
    int d4 = idx % (D_INNER / 4);
    int m  = idx / (D_INNER / 4);
    int l  = m & (SEQ - 1);
    int d0 = d4 * 4;

    float a0 = cb[d0], a1 = cb[d0 + 1], a2 = cb[d0 + 2], a3 = cb[d0 + 3];
    const float* w0 = cw + (size_t)d0 * 4;
#pragma unroll
    for (int j = 0; j < 4; ++j) {
        int ls = l - 3 + j;
        if (ls < 0) continue;
        const unsigned short* p = xz + (size_t)(m - 3 + j) * (2 * D_INNER) + d0;
        ushort4 v = *(const ushort4*)p;
        a0 += bf2f(v.x) * w0[j];
        a1 += bf2f(v.y) * w0[4 + j];
        a2 += bf2f(v.z) * w0[8 + j];
        a3 += bf2f(v.w) * w0[12 + j];
    }
    ushort4 o;
    o.x = f2bf(a0 / (1.f + __expf(-a0)));
    o.y = f2bf(a1 / (1.f + __expf(-a1)));
    o.z = f2bf(a2 / (1.f + __expf(-a2)));
    o.w = f2bf(a3 / (1.f + __expf(-a3)));
    ((ushort4*)xc)[idx] = o;
}

// ---------------- dt = softplus(dbc[:, :48] @ dtwT + dtb) ----------------
__global__ __launch_bounds__(256) void k_dt(const float* __restrict__ dbc, const float* __restrict__ dtwT,
                                            const float* __restrict__ dtb, float* __restrict__ dt)
{
    __shared__ float s[DT_RANK];
    int m = blockIdx.x;
    int t = threadIdx.x;
    if (t < DT_RANK) s[t] = dbc[(size_t)m * DBC_W + t];
    __syncthreads();
    float a[6] = {0.f, 0.f, 0.f, 0.f, 0.f, 0.f};
    for (int r = 0; r < DT_RANK; ++r) {
        float sv = s[r];
        const float* wr_ = dtwT + (size_t)r * D_INNER;
#pragma unroll
        for (int i = 0; i < 6; ++i) a[i] += sv * wr_[t + i * 256];
    }
#pragma unroll
    for (int i = 0; i < 6; ++i) {
        int d = t + i * 256;
        float x = a[i] + dtb[d];
        float sp = (x > 15.f) ? x : __logf(1.f + __expf(x));
        dt[(size_t)m * D_INNER + d] = sp;
    }
}

// ---------------- chunked selective scan ----------------
// wave-per-(4ch, chunk); 16 lanes/ch, 4 states/lane.
// FULL=false (phase 1): local scan h0=0 -> h_loc, sum(dt)
// FULL=true  (phase 3): replay from true h_in -> y * silu(z)
template<bool FULL>
__global__ __launch_bounds__(256) void k_scan_chunk(
    const float* __restrict__ dbc, const float* __restrict__ dtv_,
    const unsigned short* __restrict__ xcb, const unsigned short* __restrict__ xzb,
    const float* __restrict__ A_log, const float* __restrict__ Dskip,
    float* __restrict__ hbuf,        // !FULL: out h_loc ; FULL: in h_in
    float* __restrict__ sdtb,        // !FULL: out sum(dt)
    unsigned short* __restrict__ yg)
{
    const int lane = threadIdx.x & 63;
    const int widg = blockIdx.x * 4 + (threadIdx.x >> 6);   // 0..12287
    const int c    = widg % NCHUNK;
    const int t    = widg / NCHUNK;
    const int b    = t / (D_INNER / 4);
    const int dg   = t % (D_INNER / 4);
    const int g = lane >> 4, s = lane & 15;
    const int d = dg * 4 + g;
    const int n0 = 4 * s;

    float A2[4];
#pragma unroll
    for (int j = 0; j < 4; ++j)
        A2[j] = -__expf(A_log[(size_t)d * D_STATE + n0 + j]) * 1.4426950408889634f;
    const float Dsk = FULL ? Dskip[d] : 0.f;
    const size_t mrow = (size_t)b * SEQ + (size_t)c * CLEN;
    const size_t hidx = (((size_t)b * D_INNER + d) * NCHUNK + c) * D_STATE + n0;

    const float* Bp = dbc + mrow * DBC_W + DT_RANK + n0;
    const float* Cp = Bp + D_STATE;
    const float* dtp = dtv_ + mrow * D_INNER + d;
    const unsigned short* xcp = xcb + mrow * D_INNER + d;
    const unsigned short* zp  = xzb + mrow * (2 * D_INNER) + D_INNER + d;
    unsigned short* ygp = yg + mrow * D_INNER + d;

    float h0 = 0.f, h1 = 0.f, h2 = 0.f, h3 = 0.f;
    if (FULL) {
        float4 hi = *(const float4*)(hbuf + hidx);
        h0 = hi.x; h1 = hi.y; h2 = hi.z; h3 = hi.w;
    }
    float sdt = 0.f;

    float4 Bv = *(const float4*)Bp;
    float4 Cv = FULL ? *(const float4*)Cp : make_float4(0, 0, 0, 0);
    float dtc = *dtp;
    float xcc = bf2f(*xcp);
    float zc  = FULL ? bf2f(*zp) : 0.f;

#pragma unroll 4
    for (int l = 0; l < CLEN; ++l) {
        const int ln = (l + 1 < CLEN) ? (l + 1) : l;
        float4 Bn = *(const float4*)(Bp + (size_t)ln * DBC_W);
        float dtn = dtp[(size_t)ln * D_INNER];
        float xcn = bf2f(xcp[(size_t)ln * D_INNER]);
        float4 Cn = make_float4(0, 0, 0, 0);
        float zn = 0.f;
        if (FULL) {
            Cn = *(const float4*)(Cp + (size_t)ln * DBC_W);
            zn = bf2f(zp[(size_t)ln * (2 * D_INNER)]);
        }

        float dxc = dtc * xcc;
        if (!FULL) sdt += dtc;
        h0 = exp2f(dtc * A2[0]) * h0 + dxc * Bv.x;
        h1 = exp2f(dtc * A2[1]) * h1 + dxc * Bv.y;
        h2 = exp2f(dtc * A2[2]) * h2 + dxc * Bv.z;
        h3 = exp2f(dtc * A2[3]) * h3 + dxc * Bv.w;
        if (FULL) {
            float p = h0 * Cv.x + h1 * Cv.y + h2 * Cv.z + h3 * Cv.w;
            p = dpp_add<0xB1>(p);    // xor 1
            p = dpp_add<0x4E>(p);    // xor 2
            p = dpp_add<0x124>(p);   // row_ror:4
            p = dpp_add<0x128>(p);   // row_ror:8
            float y = p + Dsk * xcc;
            float gate = __fdividef(zc, 1.f + __expf(-zc));
            if (s == 0) ygp[(size_t)l * D_INNER] = f2bf(y * gate);
        }
        Bv = Bn; Cv = Cn; dtc = dtn; xcc = xcn; zc = zn;
    }

    if (!FULL) {
        float4 hf; hf.x = h0; hf.y = h1; hf.z = h2; hf.w = h3;
        *(float4*)(hbuf + hidx) = hf;
        if (s == 0) sdtb[((size_t)b * D_INNER + d) * NCHUNK + c] = sdt;
    }
}

// ---------------- scan phase 2: combine chunk states ----------------
__global__ __launch_bounds__(64) void k_scan_p2(
    const float* __restrict__ A_log, const float* __restrict__ sdtb,
    float* __restrict__ hbuf,        // in: h_loc ; out: h_in (in-place)
    float* __restrict__ st_out)
{
    const int lane = threadIdx.x;
    const int g = lane >> 4, s = lane & 15;
    const int bid = blockIdx.x;                    // 0..1535
    const int b = bid / (D_INNER / 4);
    const int d = (bid % (D_INNER / 4)) * 4 + g;
    const int n0 = 4 * s;

    float A2[4];
#pragma unroll
    for (int j = 0; j < 4; ++j)
        A2[j] = -__expf(A_log[(size_t)d * D_STATE + n0 + j]) * 1.4426950408889634f;

    const size_t base = ((size_t)b * D_INNER + d) * NCHUNK;
    float4 h = make_float4(0, 0, 0, 0);
#pragma unroll
    for (int c = 0; c < NCHUNK; ++c) {
        float* hp = hbuf + (base + c) * D_STATE + n0;
        float4 loc = *(const float4*)hp;
        float sdt = sdtb[base + c];
        *(float4*)hp = h;                          // h_in for chunk c
        float p0 = exp2f(sdt * A2[0]);
        float p1 = exp2f(sdt * A2[1]);
        float p2 = exp2f(sdt * A2[2]);
        float p3 = exp2f(sdt * A2[3]);
        h.x = p0 * h.x + loc.x;
        h.y = p1 * h.y + loc.y;
        h.z = p2 * h.z + loc.z;
        h.w = p3 * h.w + loc.w;
    }
    *(float4*)(st_out + ((size_t)b * D_INNER + d) * D_STATE + n0) = h;
}

// ---------------- ada: ss = cond @ ada_w^T + ada_b ----------------
__global__ void k_ada(const float* __restrict__ cond, const float* __restrict__ aw,
                      const float* __restrict__ ab, float* __restrict__ ss)
{
    __shared__ float c[D_COND];
    int bid = blockIdx.x;            // 24 = 4 batches * 6 segments
    int b = bid / 6, seg = bid % 6;
    int t = threadIdx.x;
    if (t < D_COND) c[t] = cond[b * D_COND + t];
    __syncthreads();
    int o = seg * 256 + t;
    float a = 0.f;
    const float* w = aw + (size_t)o * D_COND;
    for (int k = 0; k < D_COND; ++k) a += c[k] * w[k];
    ss[b * 2 * D_MODEL + o] = a + ab[o];
}

// ---------------- residual + LN(w,b) + LN(none)*(1+scale)+shift ----------------
__global__ __launch_bounds__(256) void k_lnmod(
    const float* __restrict__ x, const float* __restrict__ mam,
    const float* __restrict__ lnw, const float* __restrict__ lnb,
    const float* __restrict__ ss, float* __restrict__ out)
{
    int lane = threadIdx.x & 63;
    int w = threadIdx.x >> 6;
    size_t row = (size_t)blockIdx.x * 4 + w;
    int b = (int)(row >> 11);
    const float* xp = x + row * D_MODEL;
    const float* mp = mam + row * D_MODEL;
    float t[12];
    float s1 = 0.f, s2 = 0.f;
#pragma unroll
    for (int i = 0; i < 12; ++i) {
        int c = lane + i * 64;
        t[i] = xp[c] + mp[c];
        s1 += t[i]; s2 += t[i] * t[i];
    }
#pragma unroll
    for (int off = 1; off < 64; off <<= 1) { s1 += __shfl_xor(s1, off); s2 += __shfl_xor(s2, off); }
    float mean = s1 * (1.f / 768.f);
    float var  = s2 * (1.f / 768.f) - mean * mean;
    float rs = rsqrtf(var + 1e-5f);
    float u1 = 0.f, u2 = 0.f;
#pragma unroll
    for (int i = 0; i < 12; ++i) {
        int c = lane + i * 64;
        t[i] = (t[i] - mean) * rs * lnw[c] + lnb[c];
        u1 += t[i]; u2 += t[i] * t[i];
    }
#pragma unroll
    for (int off = 1; off < 64; off <<= 1) { u1 += __shfl_xor(u1, off); u2 += __shfl_xor(u2, off); }
    float m2 = u1 * (1.f / 768.f);
    float v2 = u2 * (1.f / 768.f) - m2 * m2;
    float rs2 = rsqrtf(v2 + 1e-5f);
    const float* sc = ss + (size_t)b * 2 * D_MODEL;
    const float* sh = sc + D_MODEL;
#pragma unroll
    for (int i = 0; i < 12; ++i) {
        int c = lane + i * 64;
        out[row * D_MODEL + c] = (t[i] - m2) * rs2 * (1.f + sc[c]) + sh[c];
    }
}

extern "C" void kernel_launch(void* const* d_in, const int* in_sizes, int n_in,
                              void* d_out, int out_size, void* d_ws, size_t ws_size,
                              hipStream_t stream)
{
    (void)in_sizes; (void)n_in; (void)out_size; (void)ws_size;
    const float* x    = (const float*)d_in[0];
    const float* cond = (const float*)d_in[1];
    const float* w1   = (const float*)d_in[2];
    const float* b1   = (const float*)d_in[3];
    const float* cw   = (const float*)d_in[4];
    const float* cb   = (const float*)d_in[5];
    const float* xpw  = (const float*)d_in[6];
    const float* dtw  = (const float*)d_in[7];
    const float* dtb  = (const float*)d_in[8];
    const float* Alog = (const float*)d_in[9];
    const float* Dsk  = (const float*)d_in[10];
    const float* ow   = (const float*)d_in[11];
    const float* ob   = (const float*)d_in[12];
    const float* lnw  = (const float*)d_in[13];
    const float* lnb  = (const float*)d_in[14];
    const float* aw   = (const float*)d_in[15];
    const float* ab   = (const float*)d_in[16];
    float* out = (float*)d_out;

    char* ws = (char*)d_ws;
    size_t off = 0;
    auto alloc = [&](size_t bytes) -> char* {
        off = (off + 255) & ~(size_t)255;
        char* p = ws + off;
        off += bytes;
        return p;
    };
    unsigned short* xb   = (unsigned short*)alloc((size_t)NROWS * D_MODEL * 2);      // 12.58 MB
    unsigned short* w1b  = (unsigned short*)alloc((size_t)2 * D_INNER * D_MODEL * 2);// 4.72 MB
    unsigned short* xpwb = (unsigned short*)alloc((size_t)DBC_W * D_INNER * 2);
    unsigned short* owb  = (unsigned short*)alloc((size_t)D_MODEL * D_INNER * 2);
    float*          dtwT = (float*)alloc((size_t)DT_RANK * D_INNER * 4);
    unsigned short* xzb  = (unsigned short*)alloc((size_t)NROWS * 2 * D_INNER * 2);
    unsigned short* xcb  = (unsigned short*)alloc((size_t)NROWS * D_INNER * 2);
    float*          dbc  = (float*)alloc((size_t)NROWS * DBC_W * 4);
    float*          dtb_ = (float*)alloc((size_t)NROWS * D_INNER * 4);
    unsigned short* ygb  = (unsigned short*)alloc((size_t)NROWS * D_INNER * 2);
    float*          mam  = (float*)alloc((size_t)NROWS * D_MODEL * 4);
    float*          ssb  = (float*)alloc((size_t)NBATCH * 2 * D_MODEL * 4);
    // total ~203 MB

    // scan temp buffers alias regions that are dead after in_proj:
    // hbuf (4*1536*8*64*4 = 12.58 MB) aliases xb; sdtb (196 KB) aliases w1b.
    float* hbuf = (float*)xb;
    float* sdtb = (float*)w1b;

    // prep conversions
    {
        int n4 = NROWS * D_MODEL / 4;
        k_cvt<<<(n4 + 255) / 256, 256, 0, stream>>>(x, xb, n4);
        n4 = 2 * D_INNER * D_MODEL / 4;
        k_cvt<<<(n4 + 255) / 256, 256, 0, stream>>>(w1, w1b, n4);
        n4 = DBC_W * D_INNER / 4;
        k_cvt<<<(n4 + 255) / 256, 256, 0, stream>>>(xpw, xpwb, n4);
        n4 = D_MODEL * D_INNER / 4;
        k_cvt<<<(n4 + 255) / 256, 256, 0, stream>>>(ow, owb, n4);
        k_dtw_t<<<(DT_RANK * D_INNER + 255) / 256, 256, 0, stream>>>(dtw, dtwT);
    }
    // in_proj: (8192 x 3072, K=768) -> xzb (bf16, +bias)
    k_gemm<<<dim3(2 * D_INNER / 128, NROWS / 128), 256, 0, stream>>>(
        xb, w1b, b1, nullptr, xzb, NROWS, 2 * D_INNER, D_MODEL);
    // conv + silu -> xcb
    k_conv<<<(NROWS * (D_INNER / 4) + 255) / 256, 256, 0, stream>>>(xzb, cw, cb, xcb);
    // x_proj: (8192 x 176, K=1536) -> dbc (f32)
    k_gemm<<<dim3((DBC_W + 127) / 128, NROWS / 128), 256, 0, stream>>>(
        xcb, xpwb, nullptr, dbc, nullptr, NROWS, DBC_W, D_INNER);
    // dt
    k_dt<<<NROWS, 256, 0, stream>>>(dbc, dtwT, dtb, dtb_);

    // chunked scan
    const int nwaves = NBATCH * (D_INNER / 4) * NCHUNK;   // 12288
    k_scan_chunk<false><<<nwaves / 4, 256, 0, stream>>>(
        dbc, dtb_, xcb, xzb, Alog, Dsk, hbuf, sdtb, ygb);
    k_scan_p2<<<NBATCH * (D_INNER / 4), 64, 0, stream>>>(
        Alog, sdtb, hbuf, out + (size_t)NROWS * D_MODEL);
    k_scan_chunk<true><<<nwaves / 4, 256, 0, stream>>>(
        dbc, dtb_, xcb, xzb, Alog, Dsk, hbuf, sdtb, ygb);

    // out_proj: (8192 x 768, K=1536) -> mam (f32, +bias)
    k_gemm<<<dim3(D_MODEL / 128, NROWS / 128), 256, 0, stream>>>(
        ygb, owb, ob, mam, nullptr, NROWS, D_MODEL, D_INNER);
    // ada
    k_ada<<<NBATCH * 6, 256, 0, stream>>>(cond, aw, ab, ssb);
    // residual + double LN + modulation
    k_lnmod<<<NROWS / 4, 256, 0, stream>>>(x, mam, lnw, lnb, ssb, out);
}

// Round 3
// 857.785 us; speedup vs baseline: 1.2141x; 1.1638x over previous
//
#include <hip/hip_runtime.h>
#include <hip/hip_bf16.h>
#include <cstdint>

#define D_MODEL 768
#define D_COND  128
#define D_STATE 64
#define D_CONVW 4
#define D_INNER 1536
#define DT_RANK 48
#define NBATCH  4
#define SEQ     2048
#define NROWS   (NBATCH*SEQ)          // 8192
#define DBC_W   (DT_RANK + 2*D_STATE) // 176
#define NCHUNK  8
#define CLEN    (SEQ/NCHUNK)          // 256
#define NDG     (D_INNER/4)           // 384

typedef __bf16 bf16x8 __attribute__((ext_vector_type(8)));
typedef float  f32x4  __attribute__((ext_vector_type(4)));

__device__ __forceinline__ unsigned short f2bf(float f) {
    unsigned int u = __float_as_uint(f);
    u = (u + 0x7FFFu + ((u >> 16) & 1u)) >> 16;
    return (unsigned short)u;
}
__device__ __forceinline__ float bf2f(unsigned short h) {
    return __uint_as_float(((unsigned int)h) << 16);
}

template<int CTRL>
__device__ __forceinline__ float dpp_add(float x) {
    int yi = __builtin_amdgcn_update_dpp(0, __float_as_int(x), CTRL, 0xF, 0xF, true);
    return x + __int_as_float(yi);
}

// async global->LDS, 16B per lane; LDS dest must be wave-uniform base
__device__ __forceinline__ void gl_lds16(const unsigned short* g, unsigned short* l) {
    __builtin_amdgcn_global_load_lds(
        (const __attribute__((address_space(1))) unsigned int*)g,
        (__attribute__((address_space(3))) unsigned int*)l, 16, 0, 0);
}

// ---------------- prep: f32 -> bf16 (4 elems/thread) ----------------
__global__ void k_cvt(const float* __restrict__ in, unsigned short* __restrict__ out, int n4) {
    int i = blockIdx.x * blockDim.x + threadIdx.x;
    if (i >= n4) return;
    float4 v = ((const float4*)in)[i];
    ushort4 o;
    o.x = f2bf(v.x); o.y = f2bf(v.y); o.z = f2bf(v.z); o.w = f2bf(v.w);
    ((ushort4*)out)[i] = o;
}

// dt_proj_w (1536 x 48) -> transposed f32 (48 x 1536)
__global__ void k_dtw_t(const float* __restrict__ w, float* __restrict__ wt) {
    int id = blockIdx.x * 256 + threadIdx.x;
    if (id >= DT_RANK * D_INNER) return;
    int r = id / D_INNER, d = id % D_INNER;
    wt[id] = w[d * DT_RANK + r];
}

// ---------------- MFMA bf16 GEMM: C[M,N] = A[M,K] * B[N,K]^T (+bias) ----------------
// m97 structure: 128x128 tile, BK=32, linear LDS, global_load_lds width 16.
__global__ __launch_bounds__(256) void k_gemm(
    const unsigned short* __restrict__ A,
    const unsigned short* __restrict__ B,
    const float* __restrict__ bias,
    float* __restrict__ Cf, unsigned short* __restrict__ Cb,
    int M, int N, int K)
{
    __shared__ unsigned short sA[128 * 32];
    __shared__ unsigned short sB[128 * 32];
    const int tid  = threadIdx.x;
    const int lane = tid & 63;
    const int wid  = tid >> 6;
    const int wr   = wid >> 1, wc = wid & 1;
    const int bm   = blockIdx.y, bn = blockIdx.x;

    f32x4 acc[4][4];
#pragma unroll
    for (int m = 0; m < 4; ++m)
#pragma unroll
        for (int n = 0; n < 4; ++n) { f32x4 z = {0.f,0.f,0.f,0.f}; acc[m][n] = z; }

    const int srow = (lane >> 2);          // 0..15 within a 16-row stage
    const int scol = (lane & 3) * 8;       // element offset within row (16B)
    const bf16x8* pA = (const bf16x8*)sA;  // 4 units of 8 bf16 per 32-elem row
    const bf16x8* pB = (const bf16x8*)sB;
    const int kq = lane >> 4;
    const int rr = lane & 15;

    for (int k0 = 0; k0 < K; k0 += 32) {
#pragma unroll
        for (int j = 0; j < 2; ++j) {
            int row = wid * 32 + j * 16 + srow;
            gl_lds16(A + (size_t)(bm * 128 + row) * K + k0 + scol,
                     sA + (size_t)(wid * 32 + j * 16) * 32);
            gl_lds16(B + (size_t)(bn * 128 + row) * K + k0 + scol,
                     sB + (size_t)(wid * 32 + j * 16) * 32);
        }
        __syncthreads();

        bf16x8 af[4], bg[4];
#pragma unroll
        for (int m = 0; m < 4; ++m) af[m] = pA[(wr * 64 + m * 16 + rr) * 4 + kq];
#pragma unroll
        for (int n = 0; n < 4; ++n) bg[n] = pB[(wc * 64 + n * 16 + rr) * 4 + kq];
#pragma unroll
        for (int m = 0; m < 4; ++m)
#pragma unroll
            for (int n = 0; n < 4; ++n)
                acc[m][n] = __builtin_amdgcn_mfma_f32_16x16x32_bf16(af[m], bg[n], acc[m][n], 0, 0, 0);
        __syncthreads();
    }

    const int rq = lane >> 4;
#pragma unroll
    for (int m = 0; m < 4; ++m) {
#pragma unroll
        for (int n = 0; n < 4; ++n) {
#pragma unroll
            for (int j = 0; j < 4; ++j) {
                int row  = wr * 64 + m * 16 + rq * 4 + j;
                int col  = wc * 64 + n * 16 + rr;
                int gcol = bn * 128 + col;
                if (gcol < N) {
                    size_t grow = (size_t)(bm * 128 + row);
                    float v = acc[m][n][j];
                    if (bias) v += bias[gcol];
                    if (Cf) Cf[grow * (size_t)N + gcol] = v;
                    else    Cb[grow * (size_t)N + gcol] = f2bf(v);
                }
            }
        }
    }
}

// ---------------- causal depthwise conv (w=4) + bias + SiLU -> bf16 ----------------
// also gates z in place: xz[:, D_INNER + d] <- silu(z)  (bf16)
__global__ void k_conv(unsigned short* __restrict__ xz, const float* __restrict__ cw,
                       const float* __restrict__ cb, unsigned short* __restrict__ xc)
{
    int idx = blockIdx.x * 256 + threadIdx.x;     // NROWS * 384
    if (idx >= NROWS * (D_INNER / 4)) return;
    int d4 = idx % (D_INNER / 4);
    int m  = idx / (D_INNER / 4);
    int l  = m & (SEQ - 1);
    int d0 = d4 * 4;

    float a0 = cb[d0], a1 = cb[d0 + 1], a2 = cb[d0 + 2], a3 = cb[d0 + 3];
    const float* w0 = cw + (size_t)d0 * 4;
#pragma unroll
    for (int j = 0; j < 4; ++j) {
        int ls = l - 3 + j;
        if (ls < 0) continue;
        const unsigned short* p = xz + (size_t)(m - 3 + j) * (2 * D_INNER) + d0;
        ushort4 v = *(const ushort4*)p;
        a0 += bf2f(v.x) * w0[j];
        a1 += bf2f(v.y) * w0[4 + j];
        a2 += bf2f(v.z) * w0[8 + j];
        a3 += bf2f(v.w) * w0[12 + j];
    }
    ushort4 o;
    o.x = f2bf(a0 / (1.f + __expf(-a0)));
    o.y = f2bf(a1 / (1.f + __expf(-a1)));
    o.z = f2bf(a2 / (1.f + __expf(-a2)));
    o.w = f2bf(a3 / (1.f + __expf(-a3)));
    ((ushort4*)xc)[idx] = o;

    // gate z in place
    const size_t zoff = (size_t)m * (2 * D_INNER) + D_INNER + d0;
    ushort4 z4 = *(const ushort4*)(xz + zoff);
    float z0 = bf2f(z4.x), z1 = bf2f(z4.y), z2 = bf2f(z4.z), z3 = bf2f(z4.w);
    ushort4 gv;
    gv.x = f2bf(z0 / (1.f + __expf(-z0)));
    gv.y = f2bf(z1 / (1.f + __expf(-z1)));
    gv.z = f2bf(z2 / (1.f + __expf(-z2)));
    gv.w = f2bf(z3 / (1.f + __expf(-z3)));
    *(ushort4*)(xz + zoff) = gv;
}

// ---------------- dt = softplus(dbc[:, :48] @ dtwT + dtb), 8-row tiles ----------------
__global__ __launch_bounds__(256) void k_dt(const float* __restrict__ dbc, const float* __restrict__ dtwT,
                                            const float* __restrict__ dtb, float* __restrict__ dt)
{
    __shared__ float s[8][DT_RANK];
    const int m0 = blockIdx.x * 8;
    const int t = threadIdx.x;
    for (int i = t; i < 8 * DT_RANK; i += 256) {
        int m = i / DT_RANK, r = i % DT_RANK;
        s[m][r] = dbc[(size_t)(m0 + m) * DBC_W + r];
    }
    __syncthreads();
    float acc[6][8];
#pragma unroll
    for (int i = 0; i < 6; ++i)
#pragma unroll
        for (int m = 0; m < 8; ++m) acc[i][m] = 0.f;

    for (int r = 0; r < DT_RANK; ++r) {
        float wv[6];
#pragma unroll
        for (int i = 0; i < 6; ++i) wv[i] = dtwT[(size_t)r * D_INNER + t + i * 256];
#pragma unroll
        for (int i = 0; i < 6; ++i)
#pragma unroll
            for (int m = 0; m < 8; ++m)
                acc[i][m] = fmaf(wv[i], s[m][r], acc[i][m]);
    }
#pragma unroll
    for (int i = 0; i < 6; ++i) {
        int dcol = t + i * 256;
        float bias = dtb[dcol];
#pragma unroll
        for (int m = 0; m < 8; ++m) {
            float x = acc[i][m] + bias;
            float sp = (x > 15.f) ? x : __logf(1.f + __expf(x));
            dt[(size_t)(m0 + m) * D_INNER + dcol] = sp;
        }
    }
}

// ---------------- chunked selective scan ----------------
// block = 4 consecutive d-groups, same (b, chunk) -> B/C rows shared in L1.
// FULL=false (phase 1): local scan h0=0 -> h_loc, sum(dt)
// FULL=true  (phase 3): replay from true h_in -> y * gate (gate precomputed in xz)
template<bool FULL>
__global__ __launch_bounds__(256) void k_scan_chunk(
    const float* __restrict__ dbc, const float* __restrict__ dtv_,
    const unsigned short* __restrict__ xcb, const unsigned short* __restrict__ gzb,
    const float* __restrict__ A_log, const float* __restrict__ Dskip,
    float* __restrict__ hbuf,        // !FULL: out h_loc ; FULL: in h_in
    float* __restrict__ sdtb,        // !FULL: out sum(dt)
    unsigned short* __restrict__ yg)
{
    const int lane = threadIdx.x & 63;
    const int gid  = blockIdx.x * 4 + (threadIdx.x >> 6);   // 0..12287
    const int dg   = gid % NDG;
    const int bc   = gid / NDG;
    const int b    = bc / NCHUNK;
    const int c    = bc % NCHUNK;
    const int g = lane >> 4, s = lane & 15;
    const int d = dg * 4 + g;
    const int n0 = 4 * s;

    float A2[4];
#pragma unroll
    for (int j = 0; j < 4; ++j)
        A2[j] = -__expf(A_log[(size_t)d * D_STATE + n0 + j]) * 1.4426950408889634f;
    const float Dsk = Dskip[d];
    const size_t mrow = (size_t)b * SEQ + (size_t)c * CLEN;
    const size_t hidx = (((size_t)b * D_INNER + d) * NCHUNK + c) * D_STATE + n0;

    const float* Bp  = dbc + mrow * DBC_W + DT_RANK + n0;
    const float* Cp  = Bp + D_STATE;
    const float* dtp = dtv_ + mrow * D_INNER + d;
    const unsigned short* xcp = xcb + mrow * D_INNER + d;
    const unsigned short* gp  = gzb + mrow * (2 * D_INNER) + D_INNER + d;
    unsigned short* ygp = yg + mrow * D_INNER + d;

    float h0 = 0.f, h1 = 0.f, h2 = 0.f, h3 = 0.f;
    if (FULL) {
        float4 hi = *(const float4*)(hbuf + hidx);
        h0 = hi.x; h1 = hi.y; h2 = hi.z; h3 = hi.w;
    }
    float sdt = 0.f;

    // software pipeline: hold current, prefetch next via bumped pointers.
    // (the final prefetch reads one element past the chunk; all streams are
    //  followed by other live ws allocations, values are discarded)
    float4 Bv = *(const float4*)Bp;  Bp += DBC_W;
    float dtc = *dtp;                dtp += D_INNER;
    float xcc = bf2f(*xcp);          xcp += D_INNER;
    float4 Cv; float gc = 0.f;
    if (FULL) {
        Cv = *(const float4*)Cp;     Cp += DBC_W;
        gc = bf2f(*gp);              gp += 2 * D_INNER;
    }

#pragma unroll 4
    for (int l = 0; l < CLEN; ++l) {
        float4 Bn = *(const float4*)Bp;  Bp += DBC_W;
        float dtn = *dtp;                dtp += D_INNER;
        float xcn = bf2f(*xcp);          xcp += D_INNER;
        float4 Cn; float gn = 0.f;
        if (FULL) {
            Cn = *(const float4*)Cp;     Cp += DBC_W;
            gn = bf2f(*gp);              gp += 2 * D_INNER;
        }

        float dxc = dtc * xcc;
        h0 = fmaf(exp2f(dtc * A2[0]), h0, dxc * Bv.x);
        h1 = fmaf(exp2f(dtc * A2[1]), h1, dxc * Bv.y);
        h2 = fmaf(exp2f(dtc * A2[2]), h2, dxc * Bv.z);
        h3 = fmaf(exp2f(dtc * A2[3]), h3, dxc * Bv.w);
        if (FULL) {
            float p = h0 * Cv.x;
            p = fmaf(h1, Cv.y, p);
            p = fmaf(h2, Cv.z, p);
            p = fmaf(h3, Cv.w, p);
            p = dpp_add<0xB1>(p);    // xor 1
            p = dpp_add<0x4E>(p);    // xor 2
            p = dpp_add<0x124>(p);   // row_ror:4
            p = dpp_add<0x128>(p);   // row_ror:8
            float y = fmaf(Dsk, xcc, p) * gc;
            if (s == 0) *ygp = f2bf(y);
            ygp += D_INNER;
            Cv = Cn; gc = gn;
        } else {
            sdt += dtc;
        }
        Bv = Bn; dtc = dtn; xcc = xcn;
    }

    if (!FULL) {
        float4 hf; hf.x = h0; hf.y = h1; hf.z = h2; hf.w = h3;
        *(float4*)(hbuf + hidx) = hf;
        if (s == 0) sdtb[((size_t)b * D_INNER + d) * NCHUNK + c] = sdt;
    }
}

// ---------------- scan phase 2: combine chunk states ----------------
__global__ __launch_bounds__(64) void k_scan_p2(
    const float* __restrict__ A_log, const float* __restrict__ sdtb,
    float* __restrict__ hbuf,        // in: h_loc ; out: h_in (in-place)
    float* __restrict__ st_out)
{
    const int lane = threadIdx.x;
    const int g = lane >> 4, s = lane & 15;
    const int bid = blockIdx.x;                    // 0..1535
    const int b = bid / (D_INNER / 4);
    const int d = (bid % (D_INNER / 4)) * 4 + g;
    const int n0 = 4 * s;

    float A2[4];
#pragma unroll
    for (int j = 0; j < 4; ++j)
        A2[j] = -__expf(A_log[(size_t)d * D_STATE + n0 + j]) * 1.4426950408889634f;

    const size_t base = ((size_t)b * D_INNER + d) * NCHUNK;
    float4 h = make_float4(0, 0, 0, 0);
#pragma unroll
    for (int c = 0; c < NCHUNK; ++c) {
        float* hp = hbuf + (base + c) * D_STATE + n0;
        float4 loc = *(const float4*)hp;
        float sdt = sdtb[base + c];
        *(float4*)hp = h;                          // h_in for chunk c
        float p0 = exp2f(sdt * A2[0]);
        float p1 = exp2f(sdt * A2[1]);
        float p2 = exp2f(sdt * A2[2]);
        float p3 = exp2f(sdt * A2[3]);
        h.x = p0 * h.x + loc.x;
        h.y = p1 * h.y + loc.y;
        h.z = p2 * h.z + loc.z;
        h.w = p3 * h.w + loc.w;
    }
    *(float4*)(st_out + ((size_t)b * D_INNER + d) * D_STATE + n0) = h;
}

// ---------------- ada: ss = cond @ ada_w^T + ada_b ----------------
__global__ void k_ada(const float* __restrict__ cond, const float* __restrict__ aw,
                      const float* __restrict__ ab, float* __restrict__ ss)
{
    __shared__ float c[D_COND];
    int bid = blockIdx.x;            // 24 = 4 batches * 6 segments
    int b = bid / 6, seg = bid % 6;
    int t = threadIdx.x;
    if (t < D_COND) c[t] = cond[b * D_COND + t];
    __syncthreads();
    int o = seg * 256 + t;
    float a = 0.f;
    const float* w = aw + (size_t)o * D_COND;
    for (int k = 0; k < D_COND; ++k) a += c[k] * w[k];
    ss[b * 2 * D_MODEL + o] = a + ab[o];
}

// ---------------- residual + LN(w,b) + LN(none)*(1+scale)+shift ----------------
__global__ __launch_bounds__(256) void k_lnmod(
    const float* __restrict__ x, const float* __restrict__ mam,
    const float* __restrict__ lnw, const float* __restrict__ lnb,
    const float* __restrict__ ss, float* __restrict__ out)
{
    int lane = threadIdx.x & 63;
    int w = threadIdx.x >> 6;
    size_t row = (size_t)blockIdx.x * 4 + w;
    int b = (int)(row >> 11);
    const float* xp = x + row * D_MODEL;
    const float* mp = mam + row * D_MODEL;
    float t[12];
    float s1 = 0.f, s2 = 0.f;
#pragma unroll
    for (int i = 0; i < 12; ++i) {
        int c = lane + i * 64;
        t[i] = xp[c] + mp[c];
        s1 += t[i]; s2 += t[i] * t[i];
    }
#pragma unroll
    for (int off = 1; off < 64; off <<= 1) { s1 += __shfl_xor(s1, off); s2 += __shfl_xor(s2, off); }
    float mean = s1 * (1.f / 768.f);
    float var  = s2 * (1.f / 768.f) - mean * mean;
    float rs = rsqrtf(var + 1e-5f);
    float u1 = 0.f, u2 = 0.f;
#pragma unroll
    for (int i = 0; i < 12; ++i) {
        int c = lane + i * 64;
        t[i] = (t[i] - mean) * rs * lnw[c] + lnb[c];
        u1 += t[i]; u2 += t[i] * t[i];
    }
#pragma unroll
    for (int off = 1; off < 64; off <<= 1) { u1 += __shfl_xor(u1, off); u2 += __shfl_xor(u2, off); }
    float m2 = u1 * (1.f / 768.f);
    float v2 = u2 * (1.f / 768.f) - m2 * m2;
    float rs2 = rsqrtf(v2 + 1e-5f);
    const float* sc = ss + (size_t)b * 2 * D_MODEL;
    const float* sh = sc + D_MODEL;
#pragma unroll
    for (int i = 0; i < 12; ++i) {
        int c = lane + i * 64;
        out[row * D_MODEL + c] = (t[i] - m2) * rs2 * (1.f + sc[c]) + sh[c];
    }
}

extern "C" void kernel_launch(void* const* d_in, const int* in_sizes, int n_in,
                              void* d_out, int out_size, void* d_ws, size_t ws_size,
                              hipStream_t stream)
{
    (void)in_sizes; (void)n_in; (void)out_size; (void)ws_size;
    const float* x    = (const float*)d_in[0];
    const float* cond = (const float*)d_in[1];
    const float* w1   = (const float*)d_in[2];
    const float* b1   = (const float*)d_in[3];
    const float* cw   = (const float*)d_in[4];
    const float* cb   = (const float*)d_in[5];
    const float* xpw  = (const float*)d_in[6];
    const float* dtw  = (const float*)d_in[7];
    const float* dtb  = (const float*)d_in[8];
    const float* Alog = (const float*)d_in[9];
    const float* Dsk  = (const float*)d_in[10];
    const float* ow   = (const float*)d_in[11];
    const float* ob   = (const float*)d_in[12];
    const float* lnw  = (const float*)d_in[13];
    const float* lnb  = (const float*)d_in[14];
    const float* aw   = (const float*)d_in[15];
    const float* ab   = (const float*)d_in[16];
    float* out = (float*)d_out;

    char* ws = (char*)d_ws;
    size_t off = 0;
    auto alloc = [&](size_t bytes) -> char* {
        off = (off + 255) & ~(size_t)255;
        char* p = ws + off;
        off += bytes;
        return p;
    };
    unsigned short* xb   = (unsigned short*)alloc((size_t)NROWS * D_MODEL * 2);      // 12.58 MB
    unsigned short* w1b  = (unsigned short*)alloc((size_t)2 * D_INNER * D_MODEL * 2);// 4.72 MB
    unsigned short* xpwb = (unsigned short*)alloc((size_t)DBC_W * D_INNER * 2);
    unsigned short* owb  = (unsigned short*)alloc((size_t)D_MODEL * D_INNER * 2);
    float*          dtwT = (float*)alloc((size_t)DT_RANK * D_INNER * 4);
    unsigned short* xzb  = (unsigned short*)alloc((size_t)NROWS * 2 * D_INNER * 2);
    unsigned short* xcb  = (unsigned short*)alloc((size_t)NROWS * D_INNER * 2);
    float*          dbc  = (float*)alloc((size_t)NROWS * DBC_W * 4);
    float*          dtb_ = (float*)alloc((size_t)NROWS * D_INNER * 4);
    unsigned short* ygb  = (unsigned short*)alloc((size_t)NROWS * D_INNER * 2);
    float*          mam  = (float*)alloc((size_t)NROWS * D_MODEL * 4);
    float*          ssb  = (float*)alloc((size_t)NBATCH * 2 * D_MODEL * 4);
    // total ~203 MB

    // scan temp buffers alias regions dead after in_proj:
    float* hbuf = (float*)xb;     // 12.58 MB
    float* sdtb = (float*)w1b;    // 196 KB

    // prep conversions
    {
        int n4 = NROWS * D_MODEL / 4;
        k_cvt<<<(n4 + 255) / 256, 256, 0, stream>>>(x, xb, n4);
        n4 = 2 * D_INNER * D_MODEL / 4;
        k_cvt<<<(n4 + 255) / 256, 256, 0, stream>>>(w1, w1b, n4);
        n4 = DBC_W * D_INNER / 4;
        k_cvt<<<(n4 + 255) / 256, 256, 0, stream>>>(xpw, xpwb, n4);
        n4 = D_MODEL * D_INNER / 4;
        k_cvt<<<(n4 + 255) / 256, 256, 0, stream>>>(ow, owb, n4);
        k_dtw_t<<<(DT_RANK * D_INNER + 255) / 256, 256, 0, stream>>>(dtw, dtwT);
    }
    // in_proj: (8192 x 3072, K=768) -> xzb (bf16, +bias)
    k_gemm<<<dim3(2 * D_INNER / 128, NROWS / 128), 256, 0, stream>>>(
        xb, w1b, b1, nullptr, xzb, NROWS, 2 * D_INNER, D_MODEL);
    // conv + silu -> xcb ; gate z in place
    k_conv<<<(NROWS * (D_INNER / 4) + 255) / 256, 256, 0, stream>>>(xzb, cw, cb, xcb);
    // x_proj: (8192 x 176, K=1536) -> dbc (f32)
    k_gemm<<<dim3((DBC_W + 127) / 128, NROWS / 128), 256, 0, stream>>>(
        xcb, xpwb, nullptr, dbc, nullptr, NROWS, DBC_W, D_INNER);
    // dt (8-row tiles)
    k_dt<<<NROWS / 8, 256, 0, stream>>>(dbc, dtwT, dtb, dtb_);

    // chunked scan
    const int nwaves = NBATCH * NDG * NCHUNK;   // 12288
    k_scan_chunk<false><<<nwaves / 4, 256, 0, stream>>>(
        dbc, dtb_, xcb, xzb, Alog, Dsk, hbuf, sdtb, ygb);
    k_scan_p2<<<NBATCH * NDG, 64, 0, stream>>>(
        Alog, sdtb, hbuf, out + (size_t)NROWS * D_MODEL);
    k_scan_chunk<true><<<nwaves / 4, 256, 0, stream>>>(
        dbc, dtb_, xcb, xzb, Alog, Dsk, hbuf, sdtb, ygb);

    // out_proj: (8192 x 768, K=1536) -> mam (f32, +bias)
    k_gemm<<<dim3(D_MODEL / 128, NROWS / 128), 256, 0, stream>>>(
        ygb, owb, ob, mam, nullptr, NROWS, D_MODEL, D_INNER);
    // ada
    k_ada<<<NBATCH * 6, 256, 0, stream>>>(cond, aw, ab, ssb);
    // residual + double LN + modulation
    k_lnmod<<<NROWS / 4, 256, 0, stream>>>(x, mam, lnw, lnb, ssb, out);
}